// Round 10
// baseline (177.562 us; speedup 1.0000x reference)
//
#include <hip/hip_runtime.h>

// StrictLowerTriQSM: f_{i+1} = a_i @ f_i + outer(q_i, x_i), y_i = p_i @ f_i
// N=500000, M=8, K=16. Blocked associative scan.
// Round 10: 8 chunks/wave (8-lane groups) — one LDS broadcast read serves 8
// chunks (68-float stagger -> 8 disjoint 4-bank spans, conflict-free). Each
// lane owns 2 B-columns + 1 A-column (k1) / 2 f-columns (k3). 1 element per
// stage, triple-buffered, advancing source pointers (no per-stage clamps).
// NC=32768/CH=16; ws 25.6 MB guarded with NC=16384 fallback.

#define NTOT 500000

#define AS1(p) ((const __attribute__((address_space(1))) void*)(p))
#define AS3(p) ((__attribute__((address_space(3))) void*)(p))
#define GLOAD_LDS16(gp, lp) __builtin_amdgcn_global_load_lds(AS1(gp), AS3(lp), 16, 0, 0)
#define GLOAD_LDS4(gp, lp)  __builtin_amdgcn_global_load_lds(AS1(gp), AS3(lp), 4, 0, 0)
#define WAIT_VM(n) asm volatile("s_waitcnt vmcnt(" #n ")" ::: "memory")

static __device__ __forceinline__ int iminc(int a, int b) { return a < b ? a : b; }

template<int NC> struct P {
  static constexpr int CH  = (NC == 32768) ? 16 : 32;    // elements per chunk
  static constexpr int NST = CH;                         // stages (1 elem each)
  static constexpr int NG  = NC / 64;                    // groups
  static constexpr int NS  = NG / 64;                    // supers
  static constexpr int AGGA = 0;                         // NC*64
  static constexpr int AGGB = NC * 64;                   // NC*128
  static constexpr int GAGA = NC * 192;                  // NG*64
  static constexpr int GAGB = NC * 192 + NG * 64;        // NG*128
  static constexpr int SGA  = NC * 192 + NG * 192;       // NS*64
  static constexpr int SGB  = NC * 192 + NG * 192 + NS * 64; // NS*128
  static constexpr size_t BYTES = (size_t)(NC * 192 + NG * 192 + NS * 192) * 4u;
};

// ---------------- Phase 1: per-chunk aggregates (A_blk, B_blk) -------------
// 8 chunks/wave: g = lane>>3 owns chunk wave*8+g; r = lane&7.
// Lane: B-columns r and r+8, plus A-column r, of its chunk.
// LDS buffer (floats): A[cc] @ cc*68 (544) | q[cc][m] @544 (64) |
// x[cc][k] @608 (128). BUF=736, x3 buffers, x4 waves = 35328 B.
#define K1_STEP(LB, SBa, SBb, SA, DBa, DBb, DA) do {                         \
    const float* agb_ = (LB) + g68;                                          \
    const float* qgb_ = (LB) + 544 + g8;                                     \
    const float* xgb_ = (LB) + 608 + g16r;                                   \
    const float xk0_ = xgb_[0], xk1_ = xgb_[8];                              \
    const float4 q0_ = *(const float4*)(qgb_);                               \
    const float4 q1_ = *(const float4*)(qgb_ + 4);                           \
    const float qv_[8] = {q0_.x,q0_.y,q0_.z,q0_.w,q1_.x,q1_.y,q1_.z,q1_.w};  \
    _Pragma("unroll") for (int mm = 0; mm < 8; ++mm) {                       \
      const float4 r0_ = *(const float4*)(agb_ + mm * 8);                    \
      const float4 r1_ = *(const float4*)(agb_ + mm * 8 + 4);                \
      DBa[mm] = qv_[mm] * xk0_                                               \
        + r0_.x*SBa[0] + r0_.y*SBa[1] + r0_.z*SBa[2] + r0_.w*SBa[3]          \
        + r1_.x*SBa[4] + r1_.y*SBa[5] + r1_.z*SBa[6] + r1_.w*SBa[7];         \
      DBb[mm] = qv_[mm] * xk1_                                               \
        + r0_.x*SBb[0] + r0_.y*SBb[1] + r0_.z*SBb[2] + r0_.w*SBb[3]          \
        + r1_.x*SBb[4] + r1_.y*SBb[5] + r1_.z*SBb[6] + r1_.w*SBb[7];         \
      DA[mm] =                                                               \
          r0_.x*SA[0] + r0_.y*SA[1] + r0_.z*SA[2] + r0_.w*SA[3]              \
        + r1_.x*SA[4] + r1_.y*SA[5] + r1_.z*SA[6] + r1_.w*SA[7];             \
    }                                                                        \
  } while (0)

template<int NC>
__global__ __launch_bounds__(256, 4) void k1_aggregate(
    const float* __restrict__ q, const float* __restrict__ a,
    const float* __restrict__ x, float* __restrict__ ws)
{
  using PP = P<NC>;
  constexpr int CH = PP::CH, L = PP::NST / 2;
  __shared__ float sm[4 * 3 * 736];   // 35328 B
  const int wv   = (int)(threadIdx.x >> 6);
  const int wave = blockIdx.x * 4 + wv;
  const int lane = (int)(threadIdx.x & 63);
  const int g    = lane >> 3;                    // chunk slot 0..7
  const int r    = lane & 7;                     // column role
  const int c    = wave * 8 + g;

  float* b0 = sm + wv * 2208;
  float* b1 = b0 + 736;
  float* b2 = b0 + 1472;

  const int g68 = g * 68, g8 = g * 8, g16r = g * 16 + r;

  // advancing source pointers (clamped once: junk chunks re-read tail data)
  const float* aBase[8];
#pragma unroll
  for (int cc = 0; cc < 8; ++cc)
    aBase[cc] = a + (size_t)iminc((wave * 8 + cc) * CH, NTOT - CH) * 64u + lane;
  const float* qPtr  = q + (size_t)iminc((wave * 8 + (lane >> 3)) * CH, NTOT - CH) * 8u + (lane & 7);
  const float* xPtr0 = x + (size_t)iminc((wave * 8 + (lane >> 4)) * CH, NTOT - CH) * 16u + (lane & 15);
  const float* xPtr1 = x + (size_t)iminc((wave * 8 + 4 + (lane >> 4)) * CH, NTOT - CH) * 16u + (lane & 15);
  int soff = 0;

  auto stage = [&](float* lb) {                  // 11 loads
#pragma unroll
    for (int cc = 0; cc < 8; ++cc)
      GLOAD_LDS4(aBase[cc] + soff * 64, lb + cc * 68);
    GLOAD_LDS4(qPtr, lb + 544);  qPtr  += 8;
    GLOAD_LDS4(xPtr0, lb + 608); xPtr0 += 16;
    GLOAD_LDS4(xPtr1, lb + 672); xPtr1 += 16;
    ++soff;
  };

  float sBa[8], sBb[8], sAv[8], dBa[8], dBb[8], dAv[8];
#pragma unroll
  for (int m = 0; m < 8; ++m) {
    sBa[m] = 0.f; sBb[m] = 0.f;
    sAv[m] = (m == r) ? 1.f : 0.f;               // A-agg starts as identity col
  }

  stage(b0);
  stage(b1);
#pragma unroll 1
  for (int it = 0; it < L; ++it) {
    if (it + 1 < L) { stage(b2); WAIT_VM(22); } else { WAIT_VM(11); }
    K1_STEP(b0, sBa, sBb, sAv, dBa, dBb, dAv);
    if (it + 1 < L) { stage(b0); WAIT_VM(22); } else { WAIT_VM(0); }
    K1_STEP(b1, dBa, dBb, dAv, sBa, sBb, sAv);
    float* t0 = b0; b0 = b2; b2 = b1; b1 = t0;   // (b0,b1,b2) <- (b2,b0,b1)
  }

  {
    float* dB = ws + PP::AGGB + (size_t)c * 128u;
#pragma unroll
    for (int m = 0; m < 8; ++m) dB[r * 8 + m] = sBa[m];
#pragma unroll
    for (int m = 0; m < 8; ++m) dB[(r + 8) * 8 + m] = sBb[m];
    float* dA = ws + PP::AGGA + (size_t)c * 64u + (size_t)r * 8u;
#pragma unroll
    for (int m = 0; m < 8; ++m) dA[m] = sAv[m];
  }
}

// ---------- Phase 2 generic: serial scan of 64 items per block -------------
// LV=0: chunk aggs within a group -> GAG*. LV=1: group aggs within a super
// -> SG*. IN-PLACE: item slot <- segment-local EXCLUSIVE prefix.
template<int NC, int LV>
__global__ __launch_bounds__(64) void k2scan(float* __restrict__ ws)
{
  using PP = P<NC>;
  constexpr int OFFAIN  = (LV == 0) ? PP::AGGA : PP::GAGA;
  constexpr int OFFBIN  = (LV == 0) ? PP::AGGB : PP::GAGB;
  constexpr int OFFAOUT = (LV == 0) ? PP::GAGA : PP::SGA;
  constexpr int OFFBOUT = (LV == 0) ? PP::GAGB : PP::SGB;
  __shared__ float sA[64 * 64];   // 16 KiB
  const int g    = blockIdx.x;
  const int lane = (int)(threadIdx.x & 63);
  const bool isB = lane < 16;
  const bool isA = (lane >= 16) && (lane < 24);
  const int bcol = lane & 15;
  const int acol = (lane - 16) & 7;

#pragma unroll 1
  for (int t = 0; t < 16; ++t)
    GLOAD_LDS16(ws + OFFAIN + (size_t)g * 4096u + t * 256 + lane * 4, sA + t * 256);

  float v[8];
#pragma unroll
  for (int m = 0; m < 8; ++m) v[m] = 0.f;
  if (isA) v[acol] = 1.f;

  float4 nb0, nb1;
  {
    const float* s = ws + OFFBIN + (size_t)(g * 64) * 128u + (size_t)bcol * 8u;
    nb0 = *(const float4*)s; nb1 = *(const float4*)(s + 4);
  }
  WAIT_VM(0);

#pragma unroll 1
  for (int j = 0; j < 64; ++j) {
    const int c = g * 64 + j;
    float bB[8] = {nb0.x, nb0.y, nb0.z, nb0.w, nb1.x, nb1.y, nb1.z, nb1.w};
    if (j + 1 < 64) {
      const float* s = ws + OFFBIN + (size_t)(c + 1) * 128u + (size_t)bcol * 8u;
      nb0 = *(const float4*)s; nb1 = *(const float4*)(s + 4);
    }
    if (isB) {
      float* dst = ws + OFFBIN + (size_t)c * 128u + (size_t)bcol * 8u;
#pragma unroll
      for (int m = 0; m < 8; ++m) dst[m] = v[m];
    } else if (isA) {
      float* dst = ws + OFFAIN + (size_t)c * 64u + (size_t)acol * 8u;
#pragma unroll
      for (int m = 0; m < 8; ++m) dst[m] = v[m];
    }
    const float* Aj = sA + j * 64;
    float nv[8];
#pragma unroll
    for (int m = 0; m < 8; ++m) nv[m] = 0.f;
#pragma unroll
    for (int t = 0; t < 8; ++t) {
      float4 col0 = *(const float4*)(Aj + t * 8);
      float4 col1 = *(const float4*)(Aj + t * 8 + 4);
      nv[0] += col0.x * v[t]; nv[1] += col0.y * v[t];
      nv[2] += col0.z * v[t]; nv[3] += col0.w * v[t];
      nv[4] += col1.x * v[t]; nv[5] += col1.y * v[t];
      nv[6] += col1.z * v[t]; nv[7] += col1.w * v[t];
    }
    if (isB) {
#pragma unroll
      for (int m = 0; m < 8; ++m) nv[m] += bB[m];
    }
#pragma unroll
    for (int m = 0; m < 8; ++m) v[m] = nv[m];
  }

  if (isB) {
    float* dst = ws + OFFBOUT + (size_t)g * 128u + (size_t)bcol * 8u;
#pragma unroll
    for (int m = 0; m < 8; ++m) dst[m] = v[m];
  } else if (isA) {
    float* dst = ws + OFFAOUT + (size_t)g * 64u + (size_t)acol * 8u;
#pragma unroll
    for (int m = 0; m < 8; ++m) dst[m] = v[m];
  }
}

// ---------- Phase 2c: single-wave scan over the NS super aggregates --------
template<int NC>
__global__ __launch_bounds__(64) void k2c_topscan(float* __restrict__ ws)
{
  using PP = P<NC>;
  const int lane = (int)(threadIdx.x & 63);
  const bool isB = lane < 16;
  const int bcol = lane & 15;

  float v[8];
#pragma unroll
  for (int m = 0; m < 8; ++m) v[m] = 0.f;

#pragma unroll 1
  for (int j = 0; j < PP::NS; ++j) {
    float bB[8];
    if (isB) {
      const float* s = ws + PP::SGB + (size_t)j * 128u + (size_t)bcol * 8u;
#pragma unroll
      for (int m = 0; m < 8; ++m) bB[m] = s[m];
      float* dst = ws + PP::SGB + (size_t)j * 128u + (size_t)bcol * 8u;
#pragma unroll
      for (int m = 0; m < 8; ++m) dst[m] = v[m];
    }
    const float* Aj = ws + PP::SGA + (size_t)j * 64u;
    float nv[8];
#pragma unroll
    for (int m = 0; m < 8; ++m) nv[m] = 0.f;
#pragma unroll
    for (int t = 0; t < 8; ++t) {
      float4 col0 = *(const float4*)(Aj + t * 8);
      float4 col1 = *(const float4*)(Aj + t * 8 + 4);
      nv[0] += col0.x * v[t]; nv[1] += col0.y * v[t];
      nv[2] += col0.z * v[t]; nv[3] += col0.w * v[t];
      nv[4] += col1.x * v[t]; nv[5] += col1.y * v[t];
      nv[6] += col1.z * v[t]; nv[7] += col1.w * v[t];
    }
    if (isB) {
#pragma unroll
      for (int m = 0; m < 8; ++m) nv[m] += bB[m];
    }
#pragma unroll
    for (int m = 0; m < 8; ++m) v[m] = nv[m];
  }
}

// ---------- Phase 3: replay each chunk from its carry, emit y --------------
// 8 chunks/wave: g = lane>>3 owns chunk wave*8+g; lane carries f-columns r
// and r+8. Buffer: A @cc*68 (544) | q @544+cc*8 | p @608+cc*8 | x @672+cc*16.
// BUF=800, x3, x4 waves = 38400 B.
#define K3_STEP(LB, FSa, FSb, FDa, FDb) do {                                 \
    const float* agb_ = (LB) + g68;                                          \
    const float* qgb_ = (LB) + 544 + g8;                                     \
    const float* pgb_ = (LB) + 608 + g8;                                     \
    const float* xgb_ = (LB) + 672 + g16r;                                   \
    const float xk0_ = xgb_[0], xk1_ = xgb_[8];                              \
    const float4 q0_ = *(const float4*)(qgb_);                               \
    const float4 q1_ = *(const float4*)(qgb_ + 4);                           \
    const float4 p0_ = *(const float4*)(pgb_);                               \
    const float4 p1_ = *(const float4*)(pgb_ + 4);                           \
    const float ya_ = p0_.x*FSa[0] + p0_.y*FSa[1] + p0_.z*FSa[2]             \
                    + p0_.w*FSa[3] + p1_.x*FSa[4] + p1_.y*FSa[5]             \
                    + p1_.z*FSa[6] + p1_.w*FSa[7];                           \
    const float yb_ = p0_.x*FSb[0] + p0_.y*FSb[1] + p0_.z*FSb[2]             \
                    + p0_.w*FSb[3] + p1_.x*FSb[4] + p1_.y*FSb[5]             \
                    + p1_.z*FSb[6] + p1_.w*FSb[7];                           \
    if (ti < NTOT) {                                                         \
      out[(size_t)ti * 16u + r] = ya_;                                       \
      out[(size_t)ti * 16u + r + 8] = yb_;                                   \
    }                                                                        \
    const float qv_[8] = {q0_.x,q0_.y,q0_.z,q0_.w,q1_.x,q1_.y,q1_.z,q1_.w};  \
    _Pragma("unroll") for (int mm = 0; mm < 8; ++mm) {                       \
      const float4 r0_ = *(const float4*)(agb_ + mm * 8);                    \
      const float4 r1_ = *(const float4*)(agb_ + mm * 8 + 4);                \
      FDa[mm] = qv_[mm] * xk0_                                               \
        + r0_.x*FSa[0] + r0_.y*FSa[1] + r0_.z*FSa[2] + r0_.w*FSa[3]          \
        + r1_.x*FSa[4] + r1_.y*FSa[5] + r1_.z*FSa[6] + r1_.w*FSa[7];         \
      FDb[mm] = qv_[mm] * xk1_                                               \
        + r0_.x*FSb[0] + r0_.y*FSb[1] + r0_.z*FSb[2] + r0_.w*FSb[3]          \
        + r1_.x*FSb[4] + r1_.y*FSb[5] + r1_.z*FSb[6] + r1_.w*FSb[7];         \
    }                                                                        \
    ++ti;                                                                    \
  } while (0)

template<int NC>
__global__ __launch_bounds__(256, 4) void k3_output(
    const float* __restrict__ p, const float* __restrict__ q,
    const float* __restrict__ a, const float* __restrict__ x,
    const float* __restrict__ ws, float* __restrict__ out)
{
  using PP = P<NC>;
  constexpr int CH = PP::CH, L = PP::NST / 2;
  __shared__ float sm3[4 * 3 * 800];  // 38400 B
  const int wv   = (int)(threadIdx.x >> 6);
  const int wave = blockIdx.x * 4 + wv;
  const int lane = (int)(threadIdx.x & 63);
  const int g    = lane >> 3;
  const int r    = lane & 7;
  const int c    = wave * 8 + g;
  const int gr   = c >> 6;
  const int si   = gr >> 6;

  float* b0 = sm3 + wv * 2400;
  float* b1 = b0 + 800;
  float* b2 = b0 + 1600;

  const int g68 = g * 68, g8 = g * 8, g16r = g * 16 + r;

  const float* aBase[8];
#pragma unroll
  for (int cc = 0; cc < 8; ++cc)
    aBase[cc] = a + (size_t)iminc((wave * 8 + cc) * CH, NTOT - CH) * 64u + lane;
  const float* qPtr  = q + (size_t)iminc((wave * 8 + (lane >> 3)) * CH, NTOT - CH) * 8u + (lane & 7);
  const float* pPtr  = p + (size_t)iminc((wave * 8 + (lane >> 3)) * CH, NTOT - CH) * 8u + (lane & 7);
  const float* xPtr0 = x + (size_t)iminc((wave * 8 + (lane >> 4)) * CH, NTOT - CH) * 16u + (lane & 15);
  const float* xPtr1 = x + (size_t)iminc((wave * 8 + 4 + (lane >> 4)) * CH, NTOT - CH) * 16u + (lane & 15);
  int soff = 0;

  auto stage = [&](float* lb) {                  // 12 loads
#pragma unroll
    for (int cc = 0; cc < 8; ++cc)
      GLOAD_LDS4(aBase[cc] + soff * 64, lb + cc * 68);
    GLOAD_LDS4(qPtr, lb + 544);  qPtr  += 8;
    GLOAD_LDS4(pPtr, lb + 608);  pPtr  += 8;
    GLOAD_LDS4(xPtr0, lb + 672); xPtr0 += 16;
    GLOAD_LDS4(xPtr1, lb + 736); xPtr1 += 16;
    ++soff;
  };

  stage(b0);   // issue first; f-init hides under the loads
  stage(b1);

  // f-init for columns ka=r, kb=r+8:
  // t1 = gB[:,k] + gA @ sB[:,k];  f0 = lB[:,k] + prefA_c @ t1
  const float* __restrict__ sB = ws + PP::SGB  + (size_t)si * 128u;
  const float* __restrict__ gB = ws + PP::GAGB + (size_t)gr * 128u;
  const float* __restrict__ gA = ws + PP::GAGA + (size_t)gr * 64u;
  const float* __restrict__ pA = ws + PP::AGGA + (size_t)c  * 64u;
  const float* __restrict__ lB = ws + PP::AGGB + (size_t)c  * 128u;
  float t1a[8], t1b[8];
#pragma unroll
  for (int m = 0; m < 8; ++m) { t1a[m] = gB[r * 8 + m]; t1b[m] = gB[(r + 8) * 8 + m]; }
#pragma unroll
  for (int t = 0; t < 8; ++t) {
    float4 c0 = *(const float4*)(gA + t * 8);
    float4 c1 = *(const float4*)(gA + t * 8 + 4);
    const float sa = sB[r * 8 + t], sb = sB[(r + 8) * 8 + t];
    t1a[0] += c0.x * sa; t1a[1] += c0.y * sa; t1a[2] += c0.z * sa; t1a[3] += c0.w * sa;
    t1a[4] += c1.x * sa; t1a[5] += c1.y * sa; t1a[6] += c1.z * sa; t1a[7] += c1.w * sa;
    t1b[0] += c0.x * sb; t1b[1] += c0.y * sb; t1b[2] += c0.z * sb; t1b[3] += c0.w * sb;
    t1b[4] += c1.x * sb; t1b[5] += c1.y * sb; t1b[6] += c1.z * sb; t1b[7] += c1.w * sb;
  }
  float fa0[8], fb0[8], fa1[8], fb1[8];
#pragma unroll
  for (int m = 0; m < 8; ++m) { fa0[m] = lB[r * 8 + m]; fb0[m] = lB[(r + 8) * 8 + m]; }
#pragma unroll
  for (int t = 0; t < 8; ++t) {
    float4 c0 = *(const float4*)(pA + t * 8);
    float4 c1 = *(const float4*)(pA + t * 8 + 4);
    const float ga = t1a[t], gb2 = t1b[t];
    fa0[0] += c0.x * ga; fa0[1] += c0.y * ga; fa0[2] += c0.z * ga; fa0[3] += c0.w * ga;
    fa0[4] += c1.x * ga; fa0[5] += c1.y * ga; fa0[6] += c1.z * ga; fa0[7] += c1.w * ga;
    fb0[0] += c0.x * gb2; fb0[1] += c0.y * gb2; fb0[2] += c0.z * gb2; fb0[3] += c0.w * gb2;
    fb0[4] += c1.x * gb2; fb0[5] += c1.y * gb2; fb0[6] += c1.z * gb2; fb0[7] += c1.w * gb2;
  }

  int ti = c * CH;    // true element index (junk chunks: stores guarded off)

#pragma unroll 1
  for (int it = 0; it < L; ++it) {
    if (it + 1 < L) { stage(b2); WAIT_VM(24); } else { WAIT_VM(12); }
    K3_STEP(b0, fa0, fb0, fa1, fb1);
    if (it + 1 < L) { stage(b0); WAIT_VM(24); } else { WAIT_VM(0); }
    K3_STEP(b1, fa1, fb1, fa0, fb0);
    float* t0 = b0; b0 = b2; b2 = b1; b1 = t0;
  }
}

template<int NC>
static void launch_all(const float* p, const float* q, const float* a,
                       const float* x, float* out, float* ws, hipStream_t stream)
{
  using PP = P<NC>;
  hipLaunchKernelGGL(HIP_KERNEL_NAME(k1_aggregate<NC>), dim3(NC / 32), dim3(256), 0, stream, q, a, x, ws);
  hipLaunchKernelGGL(HIP_KERNEL_NAME(k2scan<NC, 0>),    dim3(PP::NG),  dim3(64),  0, stream, ws);
  hipLaunchKernelGGL(HIP_KERNEL_NAME(k2scan<NC, 1>),    dim3(PP::NS),  dim3(64),  0, stream, ws);
  hipLaunchKernelGGL(HIP_KERNEL_NAME(k2c_topscan<NC>),  dim3(1),       dim3(64),  0, stream, ws);
  hipLaunchKernelGGL(HIP_KERNEL_NAME(k3_output<NC>),    dim3(NC / 32), dim3(256), 0, stream, p, q, a, x, ws, out);
}

extern "C" void kernel_launch(void* const* d_in, const int* in_sizes, int n_in,
                              void* d_out, int out_size, void* d_ws, size_t ws_size,
                              hipStream_t stream)
{
  const float* p = (const float*)d_in[0];
  const float* q = (const float*)d_in[1];
  const float* a = (const float*)d_in[2];
  const float* x = (const float*)d_in[3];
  float* out = (float*)d_out;
  float* ws  = (float*)d_ws;

  if (ws_size >= P<32768>::BYTES) {
    launch_all<32768>(p, q, a, x, out, ws, stream);   // 25.6 MB path
  } else {
    launch_all<16384>(p, q, a, x, out, ws, stream);   // proven 12.6 MB path
  }
}